// Round 4
// baseline (232.699 us; speedup 1.0000x reference)
//
#include <hip/hip_runtime.h>
#include <hip/hip_cooperative_groups.h>
#include <math.h>

namespace cg = cooperative_groups;

#define Nn 8192
#define Dd 256
#define Kk 32

// ws float layout:
// [0,      8192)      u4T : w transposed [d4][k][4]
// [8192,  16384)      v4T : (w*b) transposed, same layout
// [16384, 16416)      S[k]
// [16448, 278592)     gamT[k][n]   (32 * 8192 floats = 1 MB)
// [278592, 1327168)   P[k][gh][g][d]  (32*2*64*256 floats = 4 MB) partials
#define S_OFF  16384
#define GT_OFF 16448
#define P_OFF  278592

__global__ __launch_bounds__(256) void prep_kernel(const float* __restrict__ w,
                                                   const float* __restrict__ b,
                                                   float* __restrict__ ws) {
    int k = blockIdx.x, d = threadIdx.x;
    float wv = w[k * Dd + d];
    float bv = b[k * Dd + d];
    int gi = ((d >> 2) * Kk + k) * 4 + (d & 3);
    ws[gi]        = wv;        // u4T
    ws[8192 + gi] = wv * bv;   // v4T
    if (k == 0 && d < Kk) ws[S_OFF + d] = 0.f;  // S
}

__global__ __launch_bounds__(256) void fused_kernel(const float* __restrict__ x,
                                                    const float* __restrict__ w,
                                                    const float* __restrict__ b,
                                                    float* __restrict__ ws,
                                                    float* __restrict__ out) {
    __shared__ __align__(16) float uS[8192];    // 32 KB
    __shared__ __align__(16) float vS[8192];    // 32 KB
    __shared__ __align__(16) float gamB[512];   // 2 KB (phase B staging)

    float* S    = ws + S_OFF;
    float* gamT = ws + GT_OFF;
    float* P    = ws + P_OFF;

    int tid = threadIdx.x;
    int blk = blockIdx.x;

    // ================= Phase A: gamma for rows [16*blk, 16*blk+16) =========
    {
        const float4* u4 = (const float4*)ws;
        const float4* v4 = (const float4*)(ws + 8192);
        float4* uD = (float4*)uS;
        float4* vD = (float4*)vS;
        #pragma unroll
        for (int i = 0; i < 8; ++i) {
            uD[tid + 256 * i] = u4[tid + 256 * i];
            vD[tid + 256 * i] = v4[tid + 256 * i];
        }
    }
    __syncthreads();
    {
        int lane = tid & 63;
        int wave = tid >> 6;
        int k = lane & 31;
        int h = lane >> 5;
        size_t rowbase = (size_t)blk * 16 + wave * 4;   // 4 rows per wave

        const float4* uS4 = (const float4*)uS;
        const float4* vS4 = (const float4*)vS;
        const float4* xr0 = (const float4*)(x + (rowbase + 0) * Dd);
        const float4* xr1 = (const float4*)(x + (rowbase + 1) * Dd);
        const float4* xr2 = (const float4*)(x + (rowbase + 2) * Dd);
        const float4* xr3 = (const float4*)(x + (rowbase + 3) * Dd);

        float4 a0 = {0.f,0.f,0.f,0.f}, a1 = a0, a2 = a0, a3 = a0;

        #pragma unroll 4
        for (int i = 0; i < 32; ++i) {
            int ii = h * 32 + i;
            float4 u  = uS4[ii * 32 + k];
            float4 v  = vS4[ii * 32 + k];
            float4 x0 = xr0[ii];             // broadcast within half-wave
            float4 x1 = xr1[ii];
            float4 x2 = xr2[ii];
            float4 x3 = xr3[ii];
            float y;
            y = fmaf(u.x, x0.x, v.x); a0.x = fmaf(y, y, a0.x);
            y = fmaf(u.y, x0.y, v.y); a0.y = fmaf(y, y, a0.y);
            y = fmaf(u.z, x0.z, v.z); a0.z = fmaf(y, y, a0.z);
            y = fmaf(u.w, x0.w, v.w); a0.w = fmaf(y, y, a0.w);
            y = fmaf(u.x, x1.x, v.x); a1.x = fmaf(y, y, a1.x);
            y = fmaf(u.y, x1.y, v.y); a1.y = fmaf(y, y, a1.y);
            y = fmaf(u.z, x1.z, v.z); a1.z = fmaf(y, y, a1.z);
            y = fmaf(u.w, x1.w, v.w); a1.w = fmaf(y, y, a1.w);
            y = fmaf(u.x, x2.x, v.x); a2.x = fmaf(y, y, a2.x);
            y = fmaf(u.y, x2.y, v.y); a2.y = fmaf(y, y, a2.y);
            y = fmaf(u.z, x2.z, v.z); a2.z = fmaf(y, y, a2.z);
            y = fmaf(u.w, x2.w, v.w); a2.w = fmaf(y, y, a2.w);
            y = fmaf(u.x, x3.x, v.x); a3.x = fmaf(y, y, a3.x);
            y = fmaf(u.y, x3.y, v.y); a3.y = fmaf(y, y, a3.y);
            y = fmaf(u.z, x3.z, v.z); a3.z = fmaf(y, y, a3.z);
            y = fmaf(u.w, x3.w, v.w); a3.w = fmaf(y, y, a3.w);
        }

        float s0 = (a0.x + a0.y) + (a0.z + a0.w);
        float s1 = (a1.x + a1.y) + (a1.z + a1.w);
        float s2 = (a2.x + a2.y) + (a2.z + a2.w);
        float s3 = (a3.x + a3.y) + (a3.z + a3.w);
        s0 += __shfl_xor(s0, 32);
        s1 += __shfl_xor(s1, 32);
        s2 += __shfl_xor(s2, 32);
        s3 += __shfl_xor(s3, 32);
        float y40 = -0.5f * s0, y41 = -0.5f * s1, y42 = -0.5f * s2, y43 = -0.5f * s3;

        float m0 = y40, m1 = y41, m2 = y42, m3 = y43;
        #pragma unroll
        for (int o = 16; o >= 1; o >>= 1) {
            m0 = fmaxf(m0, __shfl_xor(m0, o));
            m1 = fmaxf(m1, __shfl_xor(m1, o));
            m2 = fmaxf(m2, __shfl_xor(m2, o));
            m3 = fmaxf(m3, __shfl_xor(m3, o));
        }
        float e0 = __expf(y40 - m0), e1 = __expf(y41 - m1);
        float e2 = __expf(y42 - m2), e3 = __expf(y43 - m3);
        float t0 = e0, t1 = e1, t2 = e2, t3 = e3;
        #pragma unroll
        for (int o = 16; o >= 1; o >>= 1) {
            t0 += __shfl_xor(t0, o);
            t1 += __shfl_xor(t1, o);
            t2 += __shfl_xor(t2, o);
            t3 += __shfl_xor(t3, o);
        }
        float g0 = e0 / t0, g1 = e1 / t1, g2 = e2 / t2, g3 = e3 / t3;

        if (h == 0) {
            // transposed store: gamT[k][n]
            gamT[(size_t)k * Nn + rowbase + 0] = g0;
            gamT[(size_t)k * Nn + rowbase + 1] = g1;
            gamT[(size_t)k * Nn + rowbase + 2] = g2;
            gamT[(size_t)k * Nn + rowbase + 3] = g3;
            atomicAdd(&S[k], (g0 + g1) + (g2 + g3));
        }
    }

    cg::this_grid().sync();

    // ================= Phase B: partial G/H, no atomics ====================
    // 512 blocks = 64 row-groups (128 rows) x 8 k-chunks (4 k's each)
    {
        int g  = blk >> 3;
        int k0 = (blk & 7) * 4;

        for (int e = tid; e < 512; e += 256) {
            int j = e >> 7, r = e & 127;
            gamB[r * 4 + j] = gamT[(size_t)(k0 + j) * Nn + g * 128 + r];
        }
        __syncthreads();

        float aG0 = 0.f, aG1 = 0.f, aG2 = 0.f, aG3 = 0.f;
        float aH0 = 0.f, aH1 = 0.f, aH2 = 0.f, aH3 = 0.f;
        const float4* gB4 = (const float4*)gamB;
        const float* xcol = x + (size_t)g * 128 * Dd + tid;

        for (int c = 0; c < 8; ++c) {
            float xr[16];
            #pragma unroll
            for (int r = 0; r < 16; ++r) xr[r] = xcol[(size_t)(c * 16 + r) * Dd];
            #pragma unroll
            for (int r = 0; r < 16; ++r) {
                float xv = xr[r];
                float xx = xv * xv;
                float4 gv = gB4[c * 16 + r];       // LDS broadcast
                aG0 = fmaf(gv.x, xv, aG0); aH0 = fmaf(gv.x, xx, aH0);
                aG1 = fmaf(gv.y, xv, aG1); aH1 = fmaf(gv.y, xx, aH1);
                aG2 = fmaf(gv.z, xv, aG2); aH2 = fmaf(gv.z, xx, aH2);
                aG3 = fmaf(gv.w, xv, aG3); aH3 = fmaf(gv.w, xx, aH3);
            }
        }

        // P[k][gh][g][d]
        P[((size_t)((k0 + 0) * 2 + 0) * 64 + g) * 256 + tid] = aG0;
        P[((size_t)((k0 + 0) * 2 + 1) * 64 + g) * 256 + tid] = aH0;
        P[((size_t)((k0 + 1) * 2 + 0) * 64 + g) * 256 + tid] = aG1;
        P[((size_t)((k0 + 1) * 2 + 1) * 64 + g) * 256 + tid] = aH1;
        P[((size_t)((k0 + 2) * 2 + 0) * 64 + g) * 256 + tid] = aG2;
        P[((size_t)((k0 + 2) * 2 + 1) * 64 + g) * 256 + tid] = aH2;
        P[((size_t)((k0 + 3) * 2 + 0) * 64 + g) * 256 + tid] = aG3;
        P[((size_t)((k0 + 3) * 2 + 1) * 64 + g) * 256 + tid] = aH3;
    }

    cg::this_grid().sync();

    // ================= Phase C: final reduce + epilogue ====================
    if (blk < 32) {
        int idx = blk * 256 + tid;      // 0..8191 = (k,d)
        int k = idx >> 8;
        const float* pg = P + (size_t)(k * 2 + 0) * 64 * 256 + (idx & 255);
        const float* ph = P + (size_t)(k * 2 + 1) * 64 * 256 + (idx & 255);
        float sG0 = 0.f, sG1 = 0.f, sG2 = 0.f, sG3 = 0.f;
        float sH0 = 0.f, sH1 = 0.f, sH2 = 0.f, sH3 = 0.f;
        #pragma unroll
        for (int g = 0; g < 64; g += 4) {
            sG0 += pg[(g + 0) * 256]; sH0 += ph[(g + 0) * 256];
            sG1 += pg[(g + 1) * 256]; sH1 += ph[(g + 1) * 256];
            sG2 += pg[(g + 2) * 256]; sH2 += ph[(g + 2) * 256];
            sG3 += pg[(g + 3) * 256]; sH3 += ph[(g + 3) * 256];
        }
        float Gv = (sG0 + sG1) + (sG2 + sG3);
        float Hv = (sH0 + sH1) + (sH2 + sH3);
        float sv = S[k];
        float wv = w[idx], bv = b[idx];
        const float invN = 1.0f / 8192.0f;
        const float c2 = 0.70710678118654752440f * invN;  // 1/(sqrt(2)*N)
        float mu = wv * (Gv + bv * sv) * invN;
        float w2 = wv * wv;
        float sg = (w2 * (Hv + 2.0f * bv * Gv + bv * bv * sv) - sv) * c2;
        out[idx] = sg;             // sigma_part
        out[Kk * Dd + idx] = mu;   // mu_part
    }
}

extern "C" void kernel_launch(void* const* d_in, const int* in_sizes, int n_in,
                              void* d_out, int out_size, void* d_ws, size_t ws_size,
                              hipStream_t stream) {
    const float* x = (const float*)d_in[0];
    const float* w = (const float*)d_in[1];
    const float* b = (const float*)d_in[2];
    float* out = (float*)d_out;
    float* ws = (float*)d_ws;

    hipLaunchKernelGGL(prep_kernel, dim3(Kk), dim3(256), 0, stream, w, b, ws);

    void* args[] = { (void*)&x, (void*)&w, (void*)&b, (void*)&ws, (void*)&out };
    hipLaunchCooperativeKernel((void*)fused_kernel, dim3(512), dim3(256),
                               args, 0, stream);
}

// Round 5
// 85.009 us; speedup vs baseline: 2.7373x; 2.7373x over previous
//
#include <hip/hip_runtime.h>
#include <math.h>

#define Nn 8192
#define Dd 256
#define Kk 32

// ws float layout (total 1312768 floats = 5.25 MB, <= proven R4 footprint):
// [0,       262144)   gamT[k][n]       32*8192
// [262144, 1310720)   P[k][gh][g][d]   32*2*64*256  (partial G/H, no atomics)
// [1310720,1312768)   Sp[k][g]         32*64        (partial gamma-sums)
#define GT_OFF 0
#define P_OFF  262144
#define SP_OFF 1310720

// 512 blocks x 512 threads; 8 waves x 2 rows = 16 rows/block.
// LDS = 64 KB -> 2 blocks/CU with 512-thr blocks = 16 waves/CU = 50% occupancy.
__global__ __launch_bounds__(512, 4) void gamma_kernel(const float* __restrict__ x,
                                                       const float* __restrict__ w,
                                                       const float* __restrict__ b,
                                                       float* __restrict__ ws) {
    __shared__ __align__(16) float uS[8192];   // w transposed [d4][k][4]
    __shared__ __align__(16) float vS[8192];   // w*b transposed
    float* gamT = ws + GT_OFF;
    int tid = threadIdx.x;

    // stage + transpose w, w*b into LDS (float4-vectorized; one-time cost)
    {
        const float4* w4 = (const float4*)w;
        const float4* b4 = (const float4*)b;
        float4* uD = (float4*)uS;
        float4* vD = (float4*)vS;
        #pragma unroll
        for (int i = 0; i < 4; ++i) {
            int e4 = tid + i * 512;          // 0..2047 float4s
            int k  = e4 >> 6;                // 64 float4 per k-row
            int d4 = e4 & 63;
            float4 wv = w4[e4];
            float4 bv = b4[e4];
            float4 vv = {wv.x * bv.x, wv.y * bv.y, wv.z * bv.z, wv.w * bv.w};
            uD[d4 * 32 + k] = wv;
            vD[d4 * 32 + k] = vv;
        }
    }
    __syncthreads();

    int lane = tid & 63;
    int wave = tid >> 6;
    int k = lane & 31;
    int h = lane >> 5;
    size_t rowbase = (size_t)blockIdx.x * 16 + wave * 2;

    const float4* uS4 = (const float4*)uS;
    const float4* vS4 = (const float4*)vS;
    const float4* xr0 = (const float4*)(x + (rowbase + 0) * Dd);
    const float4* xr1 = (const float4*)(x + (rowbase + 1) * Dd);

    float4 a0 = {0.f, 0.f, 0.f, 0.f}, a1 = a0;

    #pragma unroll 8
    for (int i = 0; i < 32; ++i) {
        int ii = h * 32 + i;
        float4 u  = uS4[ii * 32 + k];
        float4 v  = vS4[ii * 32 + k];
        float4 x0 = xr0[ii];                 // broadcast within half-wave
        float4 x1 = xr1[ii];
        float y;
        y = fmaf(u.x, x0.x, v.x); a0.x = fmaf(y, y, a0.x);
        y = fmaf(u.y, x0.y, v.y); a0.y = fmaf(y, y, a0.y);
        y = fmaf(u.z, x0.z, v.z); a0.z = fmaf(y, y, a0.z);
        y = fmaf(u.w, x0.w, v.w); a0.w = fmaf(y, y, a0.w);
        y = fmaf(u.x, x1.x, v.x); a1.x = fmaf(y, y, a1.x);
        y = fmaf(u.y, x1.y, v.y); a1.y = fmaf(y, y, a1.y);
        y = fmaf(u.z, x1.z, v.z); a1.z = fmaf(y, y, a1.z);
        y = fmaf(u.w, x1.w, v.w); a1.w = fmaf(y, y, a1.w);
    }

    float s0 = (a0.x + a0.y) + (a0.z + a0.w);
    float s1 = (a1.x + a1.y) + (a1.z + a1.w);
    s0 += __shfl_xor(s0, 32);                // combine the two d-halves
    s1 += __shfl_xor(s1, 32);
    float y40 = -0.5f * s0, y41 = -0.5f * s1;

    float m0 = y40, m1 = y41;
    #pragma unroll
    for (int o = 16; o >= 1; o >>= 1) {
        m0 = fmaxf(m0, __shfl_xor(m0, o));
        m1 = fmaxf(m1, __shfl_xor(m1, o));
    }
    float e0 = __expf(y40 - m0), e1 = __expf(y41 - m1);
    float t0 = e0, t1 = e1;
    #pragma unroll
    for (int o = 16; o >= 1; o >>= 1) {
        t0 += __shfl_xor(t0, o);
        t1 += __shfl_xor(t1, o);
    }
    float g0 = e0 / t0, g1 = e1 / t1;

    if (h == 0) {
        gamT[(size_t)k * Nn + rowbase + 0] = g0;   // one 64B line per (k,block)
        gamT[(size_t)k * Nn + rowbase + 1] = g1;
    }
}

// 1024 blocks x 256 thr: block = (g = blk&63 row-group of 128 rows,
// kc = blk>>6 pair of k's). g=blk&63 keeps all kc-blocks of a row-group on
// one XCD (round-robin %8) -> x served from that XCD's L2.
__global__ __launch_bounds__(256) void gh_kernel(const float* __restrict__ x,
                                                 float* __restrict__ ws) {
    const float* gamT = ws + GT_OFF;
    float* P  = ws + P_OFF;
    float* Sp = ws + SP_OFF;
    __shared__ float gamB[256];              // [r][j], r<128, j<2 (2-way = free)
    int tid = threadIdx.x;
    int g  = blockIdx.x & 63;
    int k0 = (blockIdx.x >> 6) * 2;

    {
        int j = tid >> 7, r = tid & 127;
        gamB[r * 2 + j] = gamT[(size_t)(k0 + j) * Nn + g * 128 + r];
    }
    __syncthreads();

    float aG0 = 0.f, aH0 = 0.f, aG1 = 0.f, aH1 = 0.f;
    const float* xcol = x + (size_t)g * 128 * Dd + tid;
    const float2* gB2 = (const float2*)gamB;

    for (int c = 0; c < 8; ++c) {
        float xr[16];
        #pragma unroll
        for (int r = 0; r < 16; ++r) xr[r] = xcol[(size_t)(c * 16 + r) * Dd];
        #pragma unroll
        for (int r = 0; r < 16; ++r) {
            float xv = xr[r], xx = xv * xv;
            float2 gv = gB2[c * 16 + r];     // LDS broadcast
            aG0 = fmaf(gv.x, xv, aG0); aH0 = fmaf(gv.x, xx, aH0);
            aG1 = fmaf(gv.y, xv, aG1); aH1 = fmaf(gv.y, xx, aH1);
        }
    }

    P[((size_t)((k0 + 0) * 2 + 0) * 64 + g) * 256 + tid] = aG0;
    P[((size_t)((k0 + 0) * 2 + 1) * 64 + g) * 256 + tid] = aH0;
    P[((size_t)((k0 + 1) * 2 + 0) * 64 + g) * 256 + tid] = aG1;
    P[((size_t)((k0 + 1) * 2 + 1) * 64 + g) * 256 + tid] = aH1;

    if (tid < 2) {                           // per-(k,g) gamma sums
        float s = 0.f;
        for (int r = 0; r < 128; ++r) s += gamB[r * 2 + tid];
        Sp[(k0 + tid) * 64 + g] = s;
    }
}

// 64 blocks x 256: block = (k = blk>>1, d-half = blk&1); thread = (gh, d).
__global__ __launch_bounds__(256) void red_kernel(const float* __restrict__ w,
                                                  const float* __restrict__ b,
                                                  const float* __restrict__ ws,
                                                  float* __restrict__ out) {
    const float* P  = ws + P_OFF;
    const float* Sp = ws + SP_OFF;
    __shared__ float red[256];
    __shared__ float sS;
    int tid = threadIdx.x;
    int k  = blockIdx.x >> 1;
    int dh = blockIdx.x & 1;
    int gh = tid >> 7;
    int d  = dh * 128 + (tid & 127);

    const float* p = P + (size_t)(k * 2 + gh) * 64 * 256 + d;
    float s0 = 0.f, s1 = 0.f, s2 = 0.f, s3 = 0.f;
    #pragma unroll
    for (int g = 0; g < 64; g += 4) {
        s0 += p[(g + 0) * 256];
        s1 += p[(g + 1) * 256];
        s2 += p[(g + 2) * 256];
        s3 += p[(g + 3) * 256];
    }
    red[tid] = (s0 + s1) + (s2 + s3);
    if (tid == 0) {
        float s = 0.f;
        #pragma unroll
        for (int g = 0; g < 64; ++g) s += Sp[k * 64 + g];
        sS = s;
    }
    __syncthreads();

    if (tid < 128) {
        int dd  = dh * 128 + tid;
        int idx = k * 256 + dd;
        float Gv = red[tid];            // gh = 0 half
        float Hv = red[128 + tid];      // gh = 1 half
        float sv = sS;
        float wv = w[idx], bv = b[idx];
        const float invN = 1.0f / 8192.0f;
        const float c2 = 0.70710678118654752440f * invN;   // 1/(sqrt(2)*N)
        float mu = wv * (Gv + bv * sv) * invN;
        float w2 = wv * wv;
        float sg = (w2 * (Hv + 2.0f * bv * Gv + bv * bv * sv) - sv) * c2;
        out[idx] = sg;                  // sigma_part
        out[Kk * Dd + idx] = mu;        // mu_part
    }
}

extern "C" void kernel_launch(void* const* d_in, const int* in_sizes, int n_in,
                              void* d_out, int out_size, void* d_ws, size_t ws_size,
                              hipStream_t stream) {
    const float* x = (const float*)d_in[0];
    const float* w = (const float*)d_in[1];
    const float* b = (const float*)d_in[2];
    float* out = (float*)d_out;
    float* ws = (float*)d_ws;

    hipLaunchKernelGGL(gamma_kernel, dim3(512),  dim3(512), 0, stream, x, w, b, ws);
    hipLaunchKernelGGL(gh_kernel,    dim3(1024), dim3(256), 0, stream, x, ws);
    hipLaunchKernelGGL(red_kernel,   dim3(64),   dim3(256), 0, stream, w, b, ws, out);
}